// Round 9
// baseline (618.596 us; speedup 1.0000x reference)
//
#include <hip/hip_runtime.h>

#define B 16
#define E 1024
#define T 1025
#define SP 1024
#define H 16
#define NBLK 512
#define ESTR 516

// ---- barrier area: first 16 KB of ws (uint32 indexing) ----
// leaf i counter : u[i*32]          (32 leaves, 128 B apart)
// root counter   : u[1024]
// gen            : u[1056]
// leaf release i : u[1088 + i*32]
// ---- workspace float offsets (ws = 256 MB) ----
#define OFF_X0    4096
#define OFF_U     (OFF_X0 + B*E)
#define OFF_PT    (OFF_U + B*H*E)
#define OFF_P0    (OFF_PT + B*SP*H)
#define OFF_A     (OFF_P0 + 1024)
#define OFF_POSA  (OFF_A + B*E)
#define OFF_SCP   (OFF_POSA + E*SP)
#define OFF_YP    (OFF_SCP + 32*256*SP)

// hierarchical grid barrier, monotonic epochs (1,2,3,...); zero-init per launch
__device__ __forceinline__ void gsync(unsigned* bar, int gid, unsigned epoch) {
    __syncthreads();
    if (threadIdx.x == 0) {
        __threadfence();   // release our writes
        unsigned* leaf = bar + (gid & 31) * 32;
        unsigned a = __hip_atomic_fetch_add(leaf, 1u, __ATOMIC_ACQ_REL,
                                            __HIP_MEMORY_SCOPE_AGENT) + 1u;
        if (a == epoch * 16u) {            // last of this leaf's 16 blocks
            unsigned r = __hip_atomic_fetch_add(bar + 1024, 1u, __ATOMIC_ACQ_REL,
                                                __HIP_MEMORY_SCOPE_AGENT) + 1u;
            if (r == epoch * 32u)          // last leaf
                __hip_atomic_store(bar + 1056, epoch, __ATOMIC_RELEASE,
                                   __HIP_MEMORY_SCOPE_AGENT);
        }
        if (gid < 32) {
            while (__hip_atomic_load(bar + 1056, __ATOMIC_ACQUIRE,
                                     __HIP_MEMORY_SCOPE_AGENT) < epoch)
                __builtin_amdgcn_s_sleep(8);
            __hip_atomic_store(bar + 1088 + gid * 32, epoch, __ATOMIC_RELEASE,
                               __HIP_MEMORY_SCOPE_AGENT);
        } else {
            while (__hip_atomic_load(bar + 1088 + (gid & 31) * 32, __ATOMIC_ACQUIRE,
                                     __HIP_MEMORY_SCOPE_AGENT) < epoch)
                __builtin_amdgcn_s_sleep(8);
        }
        __threadfence();   // acquire others' writes
    }
    __syncthreads();
}

__device__ __forceinline__ float blockReduceSum(float v, float* sm) {
    int tid = threadIdx.x;
    sm[tid] = v; __syncthreads();
    for (int s = 128; s > 0; s >>= 1) {
        if (tid < s) sm[tid] += sm[tid + s];
        __syncthreads();
    }
    float r = sm[0]; __syncthreads();
    return r;
}

__device__ __forceinline__ float blockReduceMax(float v, float* sm) {
    int tid = threadIdx.x;
    sm[tid] = v; __syncthreads();
    for (int s = 128; s > 0; s >>= 1) {
        if (tid < s) sm[tid] = fmaxf(sm[tid], sm[tid + s]);
        __syncthreads();
    }
    float r = sm[0]; __syncthreads();
    return r;
}

// 16 values over 64 lanes, 17 shuffles; lane l ends with full sum of value (l&15)
__device__ __forceinline__ float reduce16x64(const float v[16], int lane) {
    float r8[8], r4[4], r2[2], r1;
    {
        int bit = lane & 1;
        #pragma unroll
        for (int j = 0; j < 8; ++j) {
            float mine  = bit ? v[2*j+1] : v[2*j];
            float other = bit ? v[2*j]   : v[2*j+1];
            r8[j] = mine + __shfl_xor(other, 1, 64);
        }
    }
    {
        int bit = (lane >> 1) & 1;
        #pragma unroll
        for (int j = 0; j < 4; ++j) {
            float mine  = bit ? r8[2*j+1] : r8[2*j];
            float other = bit ? r8[2*j]   : r8[2*j+1];
            r4[j] = mine + __shfl_xor(other, 2, 64);
        }
    }
    {
        int bit = (lane >> 2) & 1;
        #pragma unroll
        for (int j = 0; j < 2; ++j) {
            float mine  = bit ? r4[2*j+1] : r4[2*j];
            float other = bit ? r4[2*j]   : r4[2*j+1];
            r2[j] = mine + __shfl_xor(other, 4, 64);
        }
    }
    {
        int bit = (lane >> 3) & 1;
        float mine  = bit ? r2[1] : r2[0];
        float other = bit ? r2[0] : r2[1];
        r1 = mine + __shfl_xor(other, 8, 64);
    }
    r1 += __shfl_xor(r1, 16, 64);
    r1 += __shfl_xor(r1, 32, 64);
    return r1;
}

// wave-per-output GEMV over 16 batches: acc[b] += wrow · xin[b]
__device__ __forceinline__ void gemv16(const float* __restrict__ wrow,
                                       const float* __restrict__ xin,
                                       float acc[16], int lane) {
    #pragma unroll
    for (int it = 0; it < 4; ++it) {
        int e4 = (it * 64 + lane) * 4;
        float4 wv = *(const float4*)(wrow + e4);
        #pragma unroll
        for (int b = 0; b < 16; ++b) {
            float4 xv = *(const float4*)(xin + (size_t)b * E + e4);
            acc[b] += wv.x * xv.x + wv.y * xv.y + wv.z * xv.z + wv.w * xv.w;
        }
    }
}

__global__ void __launch_bounds__(256, 2) k_mono(
        const float* __restrict__ x, const float* __restrict__ pos,
        const float* __restrict__ wqkv, const float* __restrict__ bqkv,
        const float* __restrict__ wc, const float* __restrict__ bc,
        float* __restrict__ out, float* __restrict__ ws) {
    const int gid = blockIdx.x;
    const int tid = threadIdx.x;
    const int wave = tid >> 6, lane = tid & 63;

    unsigned* bar = (unsigned*)ws;
    float* x0   = ws + OFF_X0;
    float* u    = ws + OFF_U;
    float* pT   = ws + OFF_PT;
    float* p0   = ws + OFF_P0;
    float* a    = ws + OFF_A;
    float* posA = ws + OFF_POSA;
    float* scp  = ws + OFF_SCP;
    float* yp   = ws + OFF_YP;

    __shared__ float smem[8 * ESTR + 128];   // 17 KB

    // ---------- P1: mean rows (32/block: 8 per wave) + posA repack ----------
    {
        #pragma unroll
        for (int r = 0; r < 8; ++r) {
            int row = gid * 32 + wave * 8 + r;      // 512*32 = 16384 = B*E rows
            int e = row & (E - 1);
            const float4* x4 = (const float4*)(x + (size_t)row * SP);
            float s = 0.f;
            #pragma unroll
            for (int it = 0; it < 4; ++it) {
                float4 v = x4[it * 64 + lane];
                s += v.x + v.y + v.z + v.w;
            }
            #pragma unroll
            for (int m = 1; m < 64; m <<= 1) s += __shfl_xor(s, m, 64);
            if (lane == 0) x0[row] = s * (1.0f / SP) + pos[(size_t)e * T];
        }
        #pragma unroll
        for (int i = 0; i < 2; ++i) {
            int e = gid * 2 + i;
            int t = tid * 4;
            const float* src = pos + (size_t)e * T + 1 + t;
            float4 v; v.x = src[0]; v.y = src[1]; v.z = src[2]; v.w = src[3];
            *(float4*)(posA + (size_t)e * SP + t) = v;
        }
    }
    gsync(bar, gid, 1u);

    // ---------- P2: per (b,h): q0 chunk in LDS, then u[b,h,:] ----------
    if (gid < 256) {
        int b = gid >> 4, h = gid & 15;
        float* xs0 = smem;          // 1024
        float* qs  = smem + 1024;   // 64
        float4 x4v = *(const float4*)(x0 + (size_t)b * E + tid * 4);
        *(float4*)&xs0[tid * 4] = x4v;
        __syncthreads();
        float accs[16];
        #pragma unroll
        for (int i = 0; i < 16; ++i) accs[i] = 0.f;
        const float* wq = wqkv + (size_t)(h * 64 + wave * 16) * E;
        #pragma unroll
        for (int i = 0; i < 16; ++i) {
            const float* wr = wq + (size_t)i * E;
            float s = 0.f;
            #pragma unroll
            for (int k = 0; k < 4; ++k) {
                int e4 = (k * 64 + lane) * 4;
                float4 wv = *(const float4*)(wr + e4);
                float4 xv = *(const float4*)&xs0[e4];
                s += wv.x * xv.x + wv.y * xv.y + wv.z * xv.z + wv.w * xv.w;
            }
            accs[i] = s;
        }
        float tot = reduce16x64(accs, lane);
        if (lane < 16) qs[wave * 16 + lane] = tot + bqkv[h * 64 + wave * 16 + lane];
        __syncthreads();
        float4 acc = make_float4(0.f, 0.f, 0.f, 0.f);
        const float* wbase = wqkv + (size_t)(E + h * 64) * E + tid * 4;
        for (int c = 0; c < 64; ++c) {
            float4 wv = *(const float4*)(wbase + (size_t)c * E);
            float qv = qs[c];
            acc.x += qv * wv.x; acc.y += qv * wv.y;
            acc.z += qv * wv.z; acc.w += qv * wv.w;
        }
        *(float4*)(u + (size_t)gid * E + tid * 4) =
            make_float4(0.125f * acc.x, 0.125f * acc.y, 0.125f * acc.z, 0.125f * acc.w);
    }
    gsync(bar, gid, 2u);

    // ---------- P3: scores partials, e-chunk 32 ----------
    {
        int es = gid >> 4;
        int b  = gid & 15;
        int e0 = es * 32;
        int t4 = tid * 4;
        float* us = smem;        // [16][32]
        #pragma unroll
        for (int k = 0; k < 2; ++k) {
            int i = k * 256 + tid;
            int h = i >> 5, el = i & 31;
            us[h * 32 + el] = u[(size_t)(b * H + h) * E + e0 + el];
        }
        __syncthreads();
        float4 acc[H];
        #pragma unroll
        for (int h = 0; h < H; ++h) acc[h] = make_float4(0.f, 0.f, 0.f, 0.f);
        for (int eq = 0; eq < 8; ++eq) {
            float4 val[4];
            #pragma unroll
            for (int j = 0; j < 4; ++j) {
                int e = e0 + eq * 4 + j;
                float4 xv = *(const float4*)(x + ((size_t)(b * E + e)) * SP + t4);
                float4 pv = *(const float4*)(posA + (size_t)e * SP + t4);
                val[j] = make_float4(xv.x + pv.x, xv.y + pv.y, xv.z + pv.z, xv.w + pv.w);
            }
            #pragma unroll
            for (int h = 0; h < H; ++h) {
                float4 uu = *(const float4*)&us[h * 32 + eq * 4];
                acc[h].x += uu.x * val[0].x + uu.y * val[1].x + uu.z * val[2].x + uu.w * val[3].x;
                acc[h].y += uu.x * val[0].y + uu.y * val[1].y + uu.z * val[2].y + uu.w * val[3].y;
                acc[h].z += uu.x * val[0].z + uu.y * val[1].z + uu.z * val[2].z + uu.w * val[3].z;
                acc[h].w += uu.x * val[0].w + uu.y * val[1].w + uu.z * val[2].w + uu.w * val[3].w;
            }
        }
        #pragma unroll
        for (int h = 0; h < H; ++h)
            *(float4*)(scp + ((size_t)(es * 256) + b * H + h) * SP + t4) = acc[h];
        __syncthreads();
    }
    gsync(bar, gid, 3u);

    // ---------- P4: softmax (256 active blocks) ----------
    if (gid < 256) {
        int bh = gid;
        int b = bh >> 4, h = bh & 15;
        float* sm = smem;
        int t4 = tid * 4;
        float4 uv = *(const float4*)(u + (size_t)bh * E + t4);
        float4 xv = *(const float4*)(x0 + (size_t)b * E + t4);
        float d = uv.x * xv.x + uv.y * xv.y + uv.z * xv.z + uv.w * xv.w;
        float s0 = blockReduceSum(d, sm);
        float4 v = make_float4(0.f, 0.f, 0.f, 0.f);
        #pragma unroll
        for (int es = 0; es < 32; ++es) {
            float4 pv = *(const float4*)(scp + ((size_t)(es * 256) + bh) * SP + t4);
            v.x += pv.x; v.y += pv.y; v.z += pv.z; v.w += pv.w;
        }
        float mx = fmaxf(fmaxf(v.x, v.y), fmaxf(v.z, v.w));
        mx = fmaxf(mx, s0);
        mx = blockReduceMax(mx, sm);
        v.x = expf(v.x - mx); v.y = expf(v.y - mx);
        v.z = expf(v.z - mx); v.w = expf(v.w - mx);
        float es0 = expf(s0 - mx);
        float sum = v.x + v.y + v.z + v.w + (tid == 0 ? es0 : 0.f);
        sum = blockReduceSum(sum, sm);
        float inv = 1.0f / sum;
        pT[((size_t)b * SP + t4 + 0) * H + h] = v.x * inv;
        pT[((size_t)b * SP + t4 + 1) * H + h] = v.y * inv;
        pT[((size_t)b * SP + t4 + 2) * H + h] = v.z * inv;
        pT[((size_t)b * SP + t4 + 3) * H + h] = v.w * inv;
        if (tid == 0) p0[bh] = es0 * inv;
    }
    gsync(bar, gid, 4u);

    // ---------- P5: y partials (t-split), LDS-transposed x ----------
    {
        int ts = gid >> 5;
        int eh = (gid >> 4) & 1;
        int b  = gid & 15;
        int e0 = eh * 512;
        float* xs  = smem;                // 8*ESTR
        float* psl = smem + 8 * ESTR;     // [8][16]
        float acc[4][8];
        #pragma unroll
        for (int j = 0; j < 4; ++j)
            #pragma unroll
            for (int i = 0; i < 8; ++i) acc[j][i] = 0.f;

        for (int ch = 0; ch < 8; ++ch) {
            int t0 = ts * 64 + ch * 8;
            __syncthreads();
            #pragma unroll
            for (int i = 0; i < 4; ++i) {
                int f4id = i * 256 + tid;
                int row = f4id >> 1;
                int c4  = (f4id & 1) * 4;
                float4 xv = *(const float4*)(x + ((size_t)(b * E + e0 + row)) * SP + t0 + c4);
                float4 pv = *(const float4*)(posA + (size_t)(e0 + row) * SP + t0 + c4);
                xs[(c4 + 0) * ESTR + row] = xv.x + pv.x;
                xs[(c4 + 1) * ESTR + row] = xv.y + pv.y;
                xs[(c4 + 2) * ESTR + row] = xv.z + pv.z;
                xs[(c4 + 3) * ESTR + row] = xv.w + pv.w;
            }
            if (tid < 32) {
                int t = tid >> 2, hq = (tid & 3) * 4;
                float4 pv = *(const float4*)(pT + ((size_t)b * SP + t0 + t) * H + hq);
                psl[t * 16 + hq + 0] = pv.x; psl[t * 16 + hq + 1] = pv.y;
                psl[t * 16 + hq + 2] = pv.z; psl[t * 16 + hq + 3] = pv.w;
            }
            __syncthreads();
            #pragma unroll
            for (int t = 0; t < 8; ++t) {
                float4 xa = *(const float4*)&xs[t * ESTR + 4 * lane];
                float4 xb = *(const float4*)&xs[t * ESTR + 256 + 4 * lane];
                float4 pq = *(const float4*)&psl[t * 16 + 4 * wave];
                float xch[8] = {xa.x, xa.y, xa.z, xa.w, xb.x, xb.y, xb.z, xb.w};
                float pch[4] = {pq.x, pq.y, pq.z, pq.w};
                #pragma unroll
                for (int j = 0; j < 4; ++j)
                    #pragma unroll
                    for (int i = 0; i < 8; ++i)
                        acc[j][i] += pch[j] * xch[i];
            }
        }
        #pragma unroll
        for (int j = 0; j < 4; ++j) {
            float* ypp = yp + (((size_t)ts * B + b) * H + 4 * wave + j) * E + e0;
            *(float4*)(ypp + 4 * lane) = make_float4(acc[j][0], acc[j][1], acc[j][2], acc[j][3]);
            *(float4*)(ypp + 256 + 4 * lane) = make_float4(acc[j][4], acc[j][5], acc[j][6], acc[j][7]);
        }
        __syncthreads();
    }
    gsync(bar, gid, 5u);

    // ---------- P6: y-reduce (LDS) + a = W_v·y + b_v (256 active blocks) ----------
    if (gid < 256) {
        int bh = gid;
        int b = bh >> 4, h = bh & 15;
        float* ys = smem;   // 1024
        int t4 = tid * 4;
        float p0v = p0[bh];
        float4 xv = *(const float4*)(x0 + (size_t)b * E + t4);
        float4 s = make_float4(p0v * xv.x, p0v * xv.y, p0v * xv.z, p0v * xv.w);
        #pragma unroll
        for (int ts = 0; ts < 16; ++ts) {
            float4 v = *(const float4*)(yp + ((size_t)(ts * 256) + bh) * E + t4);
            s.x += v.x; s.y += v.y; s.z += v.z; s.w += v.w;
        }
        *(float4*)&ys[t4] = s;
        __syncthreads();
        float xch[16];
        #pragma unroll
        for (int k = 0; k < 4; ++k) {
            float4 v = *(const float4*)&ys[lane * 16 + k * 4];
            xch[4*k+0] = v.x; xch[4*k+1] = v.y; xch[4*k+2] = v.z; xch[4*k+3] = v.w;
        }
        float accs[16];
        #pragma unroll
        for (int i = 0; i < 16; ++i) accs[i] = 0.f;
        #pragma unroll
        for (int i = 0; i < 16; ++i) {
            const float* wr = wqkv + (size_t)(2 * E + h * 64 + wave * 16 + i) * E + lane * 16;
            #pragma unroll
            for (int k = 0; k < 4; ++k) {
                float4 wv = *(const float4*)(wr + k * 4);
                accs[i] += wv.x * xch[4*k+0] + wv.y * xch[4*k+1]
                         + wv.z * xch[4*k+2] + wv.w * xch[4*k+3];
            }
        }
        float tot = reduce16x64(accs, lane);
        if (lane < 16) {
            int c = h * 64 + wave * 16 + lane;
            a[(size_t)b * E + c] = tot + bqkv[2 * E + c];
        }
        __syncthreads();
    }
    gsync(bar, gid, 6u);

    // ---------- P7: out = W_c·a + b_c (256 active blocks, wave per o) ----------
    if (gid < 256) {
        int o = gid * 4 + wave;
        float acc[16];
        #pragma unroll
        for (int b = 0; b < 16; ++b) acc[b] = 0.f;
        gemv16(wc + (size_t)o * E, a, acc, lane);
        float tot = reduce16x64(acc, lane);
        if (lane < 16) out[lane * E + o] = tot + bc[o];
    }
}

extern "C" void kernel_launch(void* const* d_in, const int* in_sizes, int n_in,
                              void* d_out, int out_size, void* d_ws, size_t ws_size,
                              hipStream_t stream) {
    const float* x    = (const float*)d_in[0];
    const float* pos  = (const float*)d_in[1];
    const float* wqkv = (const float*)d_in[2];
    const float* bqkv = (const float*)d_in[3];
    const float* wc   = (const float*)d_in[4];
    const float* bc   = (const float*)d_in[5];
    float* out = (float*)d_out;
    float* ws  = (float*)d_ws;

    hipMemsetAsync(d_ws, 0, 16384, stream);   // zero barrier area (monotonic epochs)
    k_mono<<<NBLK, 256, 0, stream>>>(x, pos, wqkv, bqkv, wc, bc, out, ws);
}

// Round 10
// 104.451 us; speedup vs baseline: 5.9223x; 5.9223x over previous
//
#include <hip/hip_runtime.h>

#define B 16
#define E 1024
#define T 1025
#define SP 1024
#define H 16
#define ESTR 516

// ---- workspace float offsets (ws = 256 MB) ----
#define OFF_X0    0
#define OFF_U     (OFF_X0 + B*E)
#define OFF_PT    (OFF_U + B*H*E)
#define OFF_P0    (OFF_PT + B*SP*H)
#define OFF_A     (OFF_P0 + 1024)
#define OFF_POSA  (OFF_A + B*E)
#define OFF_SCP   (OFF_POSA + E*SP)
#define OFF_YP    (OFF_SCP + 32*256*SP)

__device__ __forceinline__ float blockReduceSum(float v, float* sm) {
    int tid = threadIdx.x;
    sm[tid] = v; __syncthreads();
    for (int s = 128; s > 0; s >>= 1) {
        if (tid < s) sm[tid] += sm[tid + s];
        __syncthreads();
    }
    float r = sm[0]; __syncthreads();
    return r;
}

__device__ __forceinline__ float blockReduceMax(float v, float* sm) {
    int tid = threadIdx.x;
    sm[tid] = v; __syncthreads();
    for (int s = 128; s > 0; s >>= 1) {
        if (tid < s) sm[tid] = fmaxf(sm[tid], sm[tid + s]);
        __syncthreads();
    }
    float r = sm[0]; __syncthreads();
    return r;
}

// 16 values over 64 lanes, 17 shuffles; lane l ends with full sum of value (l&15)
__device__ __forceinline__ float reduce16x64(const float v[16], int lane) {
    float r8[8], r4[4], r2[2], r1;
    {
        int bit = lane & 1;
        #pragma unroll
        for (int j = 0; j < 8; ++j) {
            float mine  = bit ? v[2*j+1] : v[2*j];
            float other = bit ? v[2*j]   : v[2*j+1];
            r8[j] = mine + __shfl_xor(other, 1, 64);
        }
    }
    {
        int bit = (lane >> 1) & 1;
        #pragma unroll
        for (int j = 0; j < 4; ++j) {
            float mine  = bit ? r8[2*j+1] : r8[2*j];
            float other = bit ? r8[2*j]   : r8[2*j+1];
            r4[j] = mine + __shfl_xor(other, 2, 64);
        }
    }
    {
        int bit = (lane >> 2) & 1;
        #pragma unroll
        for (int j = 0; j < 2; ++j) {
            float mine  = bit ? r4[2*j+1] : r4[2*j];
            float other = bit ? r4[2*j]   : r4[2*j+1];
            r2[j] = mine + __shfl_xor(other, 4, 64);
        }
    }
    {
        int bit = (lane >> 3) & 1;
        float mine  = bit ? r2[1] : r2[0];
        float other = bit ? r2[0] : r2[1];
        r1 = mine + __shfl_xor(other, 8, 64);
    }
    r1 += __shfl_xor(r1, 16, 64);
    r1 += __shfl_xor(r1, 32, 64);
    return r1;
}

// wave-per-output GEMV over 16 batches: acc[b] += wrow · xin[b]
__device__ __forceinline__ void gemv16(const float* __restrict__ wrow,
                                       const float* __restrict__ xin,
                                       float acc[16], int lane) {
    #pragma unroll
    for (int it = 0; it < 4; ++it) {
        int e4 = (it * 64 + lane) * 4;
        float4 wv = *(const float4*)(wrow + e4);
        #pragma unroll
        for (int b = 0; b < 16; ++b) {
            float4 xv = *(const float4*)(xin + (size_t)b * E + e4);
            acc[b] += wv.x * xv.x + wv.y * xv.y + wv.z * xv.z + wv.w * xv.w;
        }
    }
}

// K1: blocks [0,4096): mean rows (wave per row); [4096,5120): posA repack
__global__ void k_pre(const float* __restrict__ x, const float* __restrict__ pos,
                      float* __restrict__ x0, float* __restrict__ posA) {
    int bid = blockIdx.x;
    int tid = threadIdx.x;
    if (bid < 4096) {
        int wave = tid >> 6, lane = tid & 63;
        int row = bid * 4 + wave;
        int e = row & (E - 1);
        const float4* x4 = (const float4*)(x + (size_t)row * SP);
        float s = 0.f;
        #pragma unroll
        for (int it = 0; it < 4; ++it) {
            float4 v = x4[it * 64 + lane];
            s += v.x + v.y + v.z + v.w;
        }
        #pragma unroll
        for (int m = 1; m < 64; m <<= 1) s += __shfl_xor(s, m, 64);
        if (lane == 0) x0[row] = s * (1.0f / SP) + pos[(size_t)e * T];
    } else {
        int e = bid - 4096;
        int t = tid * 4;
        const float* src = pos + (size_t)e * T + 1 + t;
        float4 v; v.x = src[0]; v.y = src[1]; v.z = src[2]; v.w = src[3];
        *(float4*)(posA + (size_t)e * SP + t) = v;
    }
}

// K2: fused q0+u per (b,h) block (verified as mono-P2)
__global__ void k_qu(const float* __restrict__ wqkv, const float* __restrict__ bqkv,
                     const float* __restrict__ x0, float* __restrict__ u) {
    int gid = blockIdx.x;
    int b = gid >> 4, h = gid & 15;
    int tid = threadIdx.x;
    int wave = tid >> 6, lane = tid & 63;
    __shared__ float xs0[1024 + 64];
    float* qs = xs0 + 1024;
    float4 x4v = *(const float4*)(x0 + (size_t)b * E + tid * 4);
    *(float4*)&xs0[tid * 4] = x4v;
    __syncthreads();
    float accs[16];
    #pragma unroll
    for (int i = 0; i < 16; ++i) accs[i] = 0.f;
    const float* wq = wqkv + (size_t)(h * 64 + wave * 16) * E;
    #pragma unroll
    for (int i = 0; i < 16; ++i) {
        const float* wr = wq + (size_t)i * E;
        float s = 0.f;
        #pragma unroll
        for (int k = 0; k < 4; ++k) {
            int e4 = (k * 64 + lane) * 4;
            float4 wv = *(const float4*)(wr + e4);
            float4 xv = *(const float4*)&xs0[e4];
            s += wv.x * xv.x + wv.y * xv.y + wv.z * xv.z + wv.w * xv.w;
        }
        accs[i] = s;
    }
    float tot = reduce16x64(accs, lane);
    if (lane < 16) qs[wave * 16 + lane] = tot + bqkv[h * 64 + wave * 16 + lane];
    __syncthreads();
    float4 acc = make_float4(0.f, 0.f, 0.f, 0.f);
    const float* wbase = wqkv + (size_t)(E + h * 64) * E + tid * 4;
    for (int c = 0; c < 64; ++c) {
        float4 wv = *(const float4*)(wbase + (size_t)c * E);
        float qv = qs[c];
        acc.x += qv * wv.x; acc.y += qv * wv.y;
        acc.z += qv * wv.z; acc.w += qv * wv.w;
    }
    *(float4*)(u + (size_t)gid * E + tid * 4) =
        make_float4(0.125f * acc.x, 0.125f * acc.y, 0.125f * acc.z, 0.125f * acc.w);
}

// K3: scores partials, e-chunk 32, 512 blocks (verified as mono-P3)
__global__ void __launch_bounds__(256, 2) k_scores(
        const float* __restrict__ x, const float* __restrict__ posA,
        const float* __restrict__ u, float* __restrict__ scp) {
    int gid = blockIdx.x;
    int es = gid >> 4;       // 0..31
    int b  = gid & 15;
    int e0 = es * 32;
    int tid = threadIdx.x;
    int t4 = tid * 4;
    __shared__ float us[H * 32];
    #pragma unroll
    for (int k = 0; k < 2; ++k) {
        int i = k * 256 + tid;
        int h = i >> 5, el = i & 31;
        us[h * 32 + el] = u[(size_t)(b * H + h) * E + e0 + el];
    }
    __syncthreads();
    float4 acc[H];
    #pragma unroll
    for (int h = 0; h < H; ++h) acc[h] = make_float4(0.f, 0.f, 0.f, 0.f);
    for (int eq = 0; eq < 8; ++eq) {
        float4 val[4];
        #pragma unroll
        for (int j = 0; j < 4; ++j) {
            int e = e0 + eq * 4 + j;
            float4 xv = *(const float4*)(x + ((size_t)(b * E + e)) * SP + t4);
            float4 pv = *(const float4*)(posA + (size_t)e * SP + t4);
            val[j] = make_float4(xv.x + pv.x, xv.y + pv.y, xv.z + pv.z, xv.w + pv.w);
        }
        #pragma unroll
        for (int h = 0; h < H; ++h) {
            float4 uu = *(const float4*)&us[h * 32 + eq * 4];
            acc[h].x += uu.x * val[0].x + uu.y * val[1].x + uu.z * val[2].x + uu.w * val[3].x;
            acc[h].y += uu.x * val[0].y + uu.y * val[1].y + uu.z * val[2].y + uu.w * val[3].y;
            acc[h].z += uu.x * val[0].z + uu.y * val[1].z + uu.z * val[2].z + uu.w * val[3].z;
            acc[h].w += uu.x * val[0].w + uu.y * val[1].w + uu.z * val[2].w + uu.w * val[3].w;
        }
    }
    #pragma unroll
    for (int h = 0; h < H; ++h)
        *(float4*)(scp + ((size_t)(es * 256) + b * H + h) * SP + t4) = acc[h];
}

// K4: softmax over 32 partials (verified as mono-P4)
__global__ void k_softmax(const float* __restrict__ u, const float* __restrict__ x0,
                          const float* __restrict__ scp, float* __restrict__ pT,
                          float* __restrict__ p0) {
    int bh = blockIdx.x;
    int b = bh >> 4, h = bh & 15;
    int tid = threadIdx.x;
    int t4 = tid * 4;
    __shared__ float sm[256];
    float4 uv = *(const float4*)(u + (size_t)bh * E + t4);
    float4 xv = *(const float4*)(x0 + (size_t)b * E + t4);
    float d = uv.x * xv.x + uv.y * xv.y + uv.z * xv.z + uv.w * xv.w;
    float s0 = blockReduceSum(d, sm);
    float4 v = make_float4(0.f, 0.f, 0.f, 0.f);
    #pragma unroll
    for (int es = 0; es < 32; ++es) {
        float4 pv = *(const float4*)(scp + ((size_t)(es * 256) + bh) * SP + t4);
        v.x += pv.x; v.y += pv.y; v.z += pv.z; v.w += pv.w;
    }
    float mx = fmaxf(fmaxf(v.x, v.y), fmaxf(v.z, v.w));
    mx = fmaxf(mx, s0);
    mx = blockReduceMax(mx, sm);
    v.x = expf(v.x - mx); v.y = expf(v.y - mx);
    v.z = expf(v.z - mx); v.w = expf(v.w - mx);
    float es0 = expf(s0 - mx);
    float sum = v.x + v.y + v.z + v.w + (tid == 0 ? es0 : 0.f);
    sum = blockReduceSum(sum, sm);
    float inv = 1.0f / sum;
    pT[((size_t)b * SP + t4 + 0) * H + h] = v.x * inv;
    pT[((size_t)b * SP + t4 + 1) * H + h] = v.y * inv;
    pT[((size_t)b * SP + t4 + 2) * H + h] = v.z * inv;
    pT[((size_t)b * SP + t4 + 3) * H + h] = v.w * inv;
    if (tid == 0) p0[bh] = es0 * inv;
}

// K5: y partials (t-split), LDS-transposed x (round-3 proven, 33 KB LDS)
__global__ void __launch_bounds__(256, 2) k_y(
        const float* __restrict__ x, const float* __restrict__ posA,
        const float* __restrict__ pT, float* __restrict__ yp) {
    int ts = blockIdx.x;
    int eh = blockIdx.y;
    int b  = blockIdx.z;
    int tid = threadIdx.x;
    int wave = tid >> 6, lane = tid & 63;
    int e0 = eh * 512;
    __shared__ float xs[16 * ESTR];
    __shared__ float psl[16][16];
    float acc[4][8];
    #pragma unroll
    for (int j = 0; j < 4; ++j)
        #pragma unroll
        for (int i = 0; i < 8; ++i) acc[j][i] = 0.f;

    for (int ch = 0; ch < 4; ++ch) {
        int t0 = ts * 64 + ch * 16;
        __syncthreads();
        #pragma unroll
        for (int i = 0; i < 8; ++i) {
            int f4id = i * 256 + tid;
            int row = f4id >> 2;
            int c4  = (f4id & 3) * 4;
            float4 xv = *(const float4*)(x + ((size_t)(b * E + e0 + row)) * SP + t0 + c4);
            float4 pv = *(const float4*)(posA + (size_t)(e0 + row) * SP + t0 + c4);
            xs[(c4 + 0) * ESTR + row] = xv.x + pv.x;
            xs[(c4 + 1) * ESTR + row] = xv.y + pv.y;
            xs[(c4 + 2) * ESTR + row] = xv.z + pv.z;
            xs[(c4 + 3) * ESTR + row] = xv.w + pv.w;
        }
        if (tid < 64) {
            int t = tid >> 2, hq = (tid & 3) * 4;
            float4 pv = *(const float4*)(pT + ((size_t)b * SP + t0 + t) * H + hq);
            psl[t][hq + 0] = pv.x; psl[t][hq + 1] = pv.y;
            psl[t][hq + 2] = pv.z; psl[t][hq + 3] = pv.w;
        }
        __syncthreads();
        #pragma unroll 4
        for (int t = 0; t < 16; ++t) {
            float4 xa = *(const float4*)&xs[t * ESTR + 4 * lane];
            float4 xb = *(const float4*)&xs[t * ESTR + 256 + 4 * lane];
            float4 pq = *(const float4*)&psl[t][4 * wave];
            float xch[8] = {xa.x, xa.y, xa.z, xa.w, xb.x, xb.y, xb.z, xb.w};
            float pch[4] = {pq.x, pq.y, pq.z, pq.w};
            #pragma unroll
            for (int j = 0; j < 4; ++j)
                #pragma unroll
                for (int i = 0; i < 8; ++i)
                    acc[j][i] += pch[j] * xch[i];
        }
    }
    #pragma unroll
    for (int j = 0; j < 4; ++j) {
        float* ypp = yp + (((size_t)ts * B + b) * H + 4 * wave + j) * E + e0;
        *(float4*)(ypp + 4 * lane) = make_float4(acc[j][0], acc[j][1], acc[j][2], acc[j][3]);
        *(float4*)(ypp + 256 + 4 * lane) = make_float4(acc[j][4], acc[j][5], acc[j][6], acc[j][7]);
    }
}

// K6: fused y-reduce + a = W_v·y + b_v (verified as mono-P6)
__global__ void k_yred_a(const float* __restrict__ yp, const float* __restrict__ p0,
                         const float* __restrict__ x0, const float* __restrict__ wqkv,
                         const float* __restrict__ bqkv, float* __restrict__ a) {
    int bh = blockIdx.x;
    int b = bh >> 4, h = bh & 15;
    int tid = threadIdx.x;
    int wave = tid >> 6, lane = tid & 63;
    __shared__ float ys[1024];
    int t4 = tid * 4;
    float p0v = p0[bh];
    float4 xv = *(const float4*)(x0 + (size_t)b * E + t4);
    float4 s = make_float4(p0v * xv.x, p0v * xv.y, p0v * xv.z, p0v * xv.w);
    #pragma unroll
    for (int ts = 0; ts < 16; ++ts) {
        float4 v = *(const float4*)(yp + ((size_t)(ts * 256) + bh) * E + t4);
        s.x += v.x; s.y += v.y; s.z += v.z; s.w += v.w;
    }
    *(float4*)&ys[t4] = s;
    __syncthreads();
    float xch[16];
    #pragma unroll
    for (int k = 0; k < 4; ++k) {
        float4 v = *(const float4*)&ys[lane * 16 + k * 4];
        xch[4*k+0] = v.x; xch[4*k+1] = v.y; xch[4*k+2] = v.z; xch[4*k+3] = v.w;
    }
    float accs[16];
    #pragma unroll
    for (int i = 0; i < 16; ++i) accs[i] = 0.f;
    #pragma unroll
    for (int i = 0; i < 16; ++i) {
        const float* wr = wqkv + (size_t)(2 * E + h * 64 + wave * 16 + i) * E + lane * 16;
        #pragma unroll
        for (int k = 0; k < 4; ++k) {
            float4 wv = *(const float4*)(wr + k * 4);
            accs[i] += wv.x * xch[4*k+0] + wv.y * xch[4*k+1]
                     + wv.z * xch[4*k+2] + wv.w * xch[4*k+3];
        }
    }
    float tot = reduce16x64(accs, lane);
    if (lane < 16) {
        int c = h * 64 + wave * 16 + lane;
        a[(size_t)b * E + c] = tot + bqkv[2 * E + c];
    }
}

// K7: out = W_c·a + b_c (wave per o)
__global__ void k_out(const float* __restrict__ wc, const float* __restrict__ bc,
                      const float* __restrict__ a, float* __restrict__ out) {
    int wave = threadIdx.x >> 6, lane = threadIdx.x & 63;
    int o = blockIdx.x * 4 + wave;
    float acc[16];
    #pragma unroll
    for (int b = 0; b < 16; ++b) acc[b] = 0.f;
    gemv16(wc + (size_t)o * E, a, acc, lane);
    float tot = reduce16x64(acc, lane);
    if (lane < 16) out[lane * E + o] = tot + bc[o];
}

extern "C" void kernel_launch(void* const* d_in, const int* in_sizes, int n_in,
                              void* d_out, int out_size, void* d_ws, size_t ws_size,
                              hipStream_t stream) {
    const float* x    = (const float*)d_in[0];
    const float* pos  = (const float*)d_in[1];
    const float* wqkv = (const float*)d_in[2];
    const float* bqkv = (const float*)d_in[3];
    const float* wc   = (const float*)d_in[4];
    const float* bc   = (const float*)d_in[5];
    float* out = (float*)d_out;
    float* ws  = (float*)d_ws;

    float* x0   = ws + OFF_X0;
    float* u    = ws + OFF_U;
    float* pT   = ws + OFF_PT;
    float* p0   = ws + OFF_P0;
    float* a    = ws + OFF_A;
    float* posA = ws + OFF_POSA;
    float* scp  = ws + OFF_SCP;
    float* yp   = ws + OFF_YP;

    k_pre<<<5120, 256, 0, stream>>>(x, pos, x0, posA);
    k_qu<<<256, 256, 0, stream>>>(wqkv, bqkv, x0, u);
    k_scores<<<512, 256, 0, stream>>>(x, posA, u, scp);
    k_softmax<<<256, 256, 0, stream>>>(u, x0, scp, pT, p0);
    k_y<<<dim3(16, 2, B), 256, 0, stream>>>(x, posA, pT, yp);
    k_yred_a<<<256, 256, 0, stream>>>(yp, p0, x0, wqkv, bqkv, a);
    k_out<<<256, 256, 0, stream>>>(wc, bc, a, out);
}